// Round 1
// baseline (282.512 us; speedup 1.0000x reference)
//
#include <hip/hip_runtime.h>

// out[row, :] = p_gen[row] * vocab_ds[row, :]                      (phase 1)
// out[row, src[l, row%B]] = p_gen*vd[...] + (1-p_gen)*attns[row,l] (phase 2,
//     last-occurrence-of-duplicate wins, matching sequential scatter .set)
__global__ __launch_bounds__(256) void distgen_kernel(
    const float* __restrict__ vocab_ds,
    const float* __restrict__ attns,
    const float* __restrict__ p_gens,
    const int*   __restrict__ sources,
    float* __restrict__ out,
    int V, int L, int B)
{
    const int row = blockIdx.x;
    const int tid = threadIdx.x;
    const size_t base = (size_t)row * (size_t)V;
    const float pg = p_gens[row];

    // ---------- phase 1: vectorized row scale ----------
    // Row base element index may not be 16B-aligned (V odd). Scalar prologue
    // up to the global 16B boundary, float4 bulk, scalar tail.
    const int mis  = (int)(base & 3);
    const int pre  = mis ? (4 - mis) : 0;
    const int preN = pre < V ? pre : V;
    for (int j = tid; j < preN; j += blockDim.x)
        out[base + j] = pg * vocab_ds[base + j];

    const int rem  = V - preN;
    const int nvec = rem >> 2;
    const float4* __restrict__ v4 = (const float4*)(vocab_ds + base + preN);
    float4* __restrict__ o4       = (float4*)(out + base + preN);
    for (int i = tid; i < nvec; i += blockDim.x) {
        float4 x = v4[i];
        x.x *= pg; x.y *= pg; x.z *= pg; x.w *= pg;
        o4[i] = x;
    }
    for (int j = preN + (nvec << 2) + tid; j < V; j += blockDim.x)
        out[base + j] = pg * vocab_ds[base + j];

    // ---------- phase 2: scatter (overwrite, last dup wins) ----------
    __shared__ int s_src[512];
    const int b = row % B;
    const bool use_lds = (L <= 512);
    if (use_lds) {
        for (int l = tid; l < L; l += blockDim.x)
            s_src[l] = sources[(size_t)l * B + b];
    }
    __syncthreads();   // also orders phase-1 stores before phase-2 stores

    const float gate = 1.0f - pg;
    for (int l = tid; l < L; l += blockDim.x) {
        const int v = use_lds ? s_src[l] : sources[(size_t)l * B + b];
        if (v < 0 || v >= V) continue;          // mode="drop" safety
        bool last = true;
        if (use_lds) {
            for (int l2 = l + 1; l2 < L; ++l2)
                if (s_src[l2] == v) { last = false; break; }
        } else {
            for (int l2 = l + 1; l2 < L; ++l2)
                if (sources[(size_t)l2 * B + b] == v) { last = false; break; }
        }
        if (last) {
            const float a = gate * attns[(size_t)row * L + l];
            out[base + v] = pg * vocab_ds[base + v] + a;
        }
    }
}

extern "C" void kernel_launch(void* const* d_in, const int* in_sizes, int n_in,
                              void* d_out, int out_size, void* d_ws, size_t ws_size,
                              hipStream_t stream) {
    const float* vocab_ds = (const float*)d_in[0];
    const float* attns    = (const float*)d_in[1];
    const float* p_gens   = (const float*)d_in[2];
    const int*   sources  = (const int*)d_in[3];
    // in_sizes: [rows*V, rows*L, rows, L*B, 1]
    const int rows = in_sizes[2];
    const int V    = in_sizes[0] / rows;
    const int L    = in_sizes[1] / rows;
    const int B    = in_sizes[3] / L;
    float* out = (float*)d_out;

    distgen_kernel<<<rows, 256, 0, stream>>>(vocab_ds, attns, p_gens, sources,
                                             out, V, L, B);
}

// Round 3
// 248.642 us; speedup vs baseline: 1.1362x; 1.1362x over previous
//
#include <hip/hip_runtime.h>

typedef float f32x4 __attribute__((ext_vector_type(4)));

// ---------------------------------------------------------------------------
// Kernel A: per source column b, mark last occurrence of each vocab id.
// vlast[l*B+b] = sources[l*B+b] if position l is the LAST occurrence of that
// id in column b, else -1. Only B=32 columns exist (rows share columns mod B).
// ---------------------------------------------------------------------------
#define LMAX 1024

__global__ __launch_bounds__(256) void mask_kernel(
    const int* __restrict__ sources, int* __restrict__ vlast, int L, int B)
{
    const int b = blockIdx.x;
    __shared__ int s_col[LMAX];
    const bool use_lds = (L <= LMAX);
    if (use_lds) {
        for (int l = threadIdx.x; l < L; l += blockDim.x)
            s_col[l] = sources[(size_t)l * B + b];
    }
    __syncthreads();
    for (int l = threadIdx.x; l < L; l += blockDim.x) {
        const int v = use_lds ? s_col[l] : sources[(size_t)l * B + b];
        int keep = v;
        if (use_lds) {
            for (int l2 = l + 1; l2 < L; ++l2)
                if (s_col[l2] == v) { keep = -1; break; }
        } else {
            for (int l2 = l + 1; l2 < L; ++l2)
                if (sources[(size_t)l2 * B + b] == v) { keep = -1; break; }
        }
        vlast[(size_t)l * B + b] = keep;
    }
}

// ---------------------------------------------------------------------------
// Kernel B: pure streaming scale  out[row,:] = pg[row] * vd[row,:]
// One block per row; f32x4 main body with manual unroll; nontemporal stores
// so the output stream does not evict vocab_ds from L3 between graph replays.
// ---------------------------------------------------------------------------
__global__ __launch_bounds__(256) void scale_kernel(
    const float* __restrict__ vd, const float* __restrict__ pgs,
    float* __restrict__ out, int V)
{
    const int row = blockIdx.x;
    const int tid = threadIdx.x;
    const size_t base = (size_t)row * (size_t)V;
    const float pg = pgs[row];

    // peel to 16B alignment (V odd -> row bases rotate mod 4 elements)
    const int mis  = (int)(base & 3);
    const int pre  = mis ? (4 - mis) : 0;
    const int preN = pre < V ? pre : V;
    for (int j = tid; j < preN; j += 256)
        __builtin_nontemporal_store(pg * vd[base + j], &out[base + j]);

    const int nvec = (V - preN) >> 2;
    const f32x4* __restrict__ v4 = (const f32x4*)(vd + base + preN);
    f32x4* __restrict__ o4       = (f32x4*)(out + base + preN);

    int i = tid;
    for (; i + 3 * 256 < nvec; i += 4 * 256) {
        f32x4 a = v4[i];
        f32x4 b = v4[i + 256];
        f32x4 c = v4[i + 512];
        f32x4 d = v4[i + 768];
        a *= pg; b *= pg; c *= pg; d *= pg;
        __builtin_nontemporal_store(a, &o4[i]);
        __builtin_nontemporal_store(b, &o4[i + 256]);
        __builtin_nontemporal_store(c, &o4[i + 512]);
        __builtin_nontemporal_store(d, &o4[i + 768]);
    }
    for (; i < nvec; i += 256) {
        f32x4 a = v4[i];
        a *= pg;
        __builtin_nontemporal_store(a, &o4[i]);
    }
    for (int j = preN + (nvec << 2) + tid; j < V; j += 256)
        __builtin_nontemporal_store(pg * vd[base + j], &out[base + j]);
}

// ---------------------------------------------------------------------------
// Kernel C: scatter. Mask guarantees one writer per (row, vocab slot), so all
// stores are independent: out[row, v] = pg*vd[row, v] + (1-pg)*attns[row, l].
// ---------------------------------------------------------------------------
__global__ __launch_bounds__(128) void scatter_kernel(
    const float* __restrict__ vd, const float* __restrict__ attns,
    const float* __restrict__ pgs, const int* __restrict__ vlast,
    float* __restrict__ out, int V, int L, int B)
{
    const int row = blockIdx.x;
    const int b = row % B;
    const float pg = pgs[row];
    const float gate = 1.0f - pg;
    const size_t base = (size_t)row * (size_t)V;
    for (int l = threadIdx.x; l < L; l += 128) {
        const int v = vlast[(size_t)l * B + b];
        if (v >= 0 && v < V)
            out[base + v] = fmaf(pg, vd[base + v],
                                 gate * attns[(size_t)row * L + l]);
    }
}

// ---------------------------------------------------------------------------
// Fallback (round-1 fused kernel) if d_ws is too small for the mask.
// ---------------------------------------------------------------------------
__global__ __launch_bounds__(256) void fused_fallback_kernel(
    const float* __restrict__ vocab_ds, const float* __restrict__ attns,
    const float* __restrict__ p_gens, const int* __restrict__ sources,
    float* __restrict__ out, int V, int L, int B)
{
    const int row = blockIdx.x;
    const int tid = threadIdx.x;
    const size_t base = (size_t)row * (size_t)V;
    const float pg = p_gens[row];

    const int mis  = (int)(base & 3);
    const int pre  = mis ? (4 - mis) : 0;
    const int preN = pre < V ? pre : V;
    for (int j = tid; j < preN; j += blockDim.x)
        out[base + j] = pg * vocab_ds[base + j];
    const int nvec = (V - preN) >> 2;
    const f32x4* __restrict__ v4 = (const f32x4*)(vocab_ds + base + preN);
    f32x4* __restrict__ o4       = (f32x4*)(out + base + preN);
    for (int i = tid; i < nvec; i += blockDim.x) {
        f32x4 x = v4[i];
        x *= pg;
        o4[i] = x;
    }
    for (int j = preN + (nvec << 2) + tid; j < V; j += blockDim.x)
        out[base + j] = pg * vocab_ds[base + j];

    __shared__ int s_src[512];
    const int b = row % B;
    const bool use_lds = (L <= 512);
    if (use_lds) {
        for (int l = tid; l < L; l += blockDim.x)
            s_src[l] = sources[(size_t)l * B + b];
    }
    __syncthreads();
    const float gate = 1.0f - pg;
    for (int l = tid; l < L; l += blockDim.x) {
        const int v = use_lds ? s_src[l] : sources[(size_t)l * B + b];
        if (v < 0 || v >= V) continue;
        bool last = true;
        for (int l2 = l + 1; l2 < L; ++l2) {
            const int v2 = use_lds ? s_src[l2] : sources[(size_t)l2 * B + b];
            if (v2 == v) { last = false; break; }
        }
        if (last) {
            const float a = gate * attns[(size_t)row * L + l];
            out[base + v] = pg * vocab_ds[base + v] + a;
        }
    }
}

extern "C" void kernel_launch(void* const* d_in, const int* in_sizes, int n_in,
                              void* d_out, int out_size, void* d_ws, size_t ws_size,
                              hipStream_t stream) {
    const float* vocab_ds = (const float*)d_in[0];
    const float* attns    = (const float*)d_in[1];
    const float* p_gens   = (const float*)d_in[2];
    const int*   sources  = (const int*)d_in[3];
    const int rows = in_sizes[2];
    const int V    = in_sizes[0] / rows;
    const int L    = in_sizes[1] / rows;
    const int B    = in_sizes[3] / L;
    float* out = (float*)d_out;

    const size_t mask_bytes = (size_t)L * (size_t)B * sizeof(int);
    if (ws_size >= mask_bytes) {
        int* vlast = (int*)d_ws;
        mask_kernel<<<B, 256, 0, stream>>>(sources, vlast, L, B);
        scale_kernel<<<rows, 256, 0, stream>>>(vocab_ds, p_gens, out, V);
        scatter_kernel<<<rows, 128, 0, stream>>>(vocab_ds, attns, p_gens,
                                                 vlast, out, V, L, B);
    } else {
        fused_fallback_kernel<<<rows, 256, 0, stream>>>(
            vocab_ds, attns, p_gens, sources, out, V, L, B);
    }
}